// Round 4
// baseline (734.001 us; speedup 1.0000x reference)
//
#include <hip/hip_runtime.h>
#include <hip/hip_bf16.h>

typedef unsigned short u16;
typedef __attribute__((ext_vector_type(8))) short short8;
typedef __attribute__((ext_vector_type(4))) float f32x4;

#define NN   100000
#define NE   1600000
#define DIN  512
#define DHID 128
#define DOUT 40
#define NB   98          // ceil(NN / 1024) scan blocks

__device__ __forceinline__ float bf2f(u16 u) {
  union { unsigned int i; float f; } v; v.i = ((unsigned int)u) << 16; return v.f;
}
__device__ __forceinline__ u16 f2bf(float f) {
  __hip_bfloat16 h = __float2bfloat16(f);
  return *reinterpret_cast<u16*>(&h);
}

// ---------------- graph build ----------------
// dtypes (HW-verified): ei int32, x/W1/b1/W2/b2 fp32, d_out fp32.
// CSR bucket order is irrelevant (we only sum over edges). Ticket array dropped:
// k_scatter takes its within-bucket slot from an atomicAdd on a cursor array
// (cur = copy of offs, written for free by k_scan3). Saves 12.8 MB traffic.
// Edge record packed as int2{src, float_bits(dinv[src])}.

__global__ __launch_bounds__(256) void k_count(const int* __restrict__ ei, int* __restrict__ cnt) {
  int base = (blockIdx.x * 256 + threadIdx.x) * 4;
  if (base >= NE) return;
  int4 d4 = *(const int4*)&ei[NE + base];
  atomicAdd(&cnt[d4.x], 1);    // 4 independent atomics in flight
  atomicAdd(&cnt[d4.y], 1);
  atomicAdd(&cnt[d4.z], 1);
  atomicAdd(&cnt[d4.w], 1);
}

__global__ __launch_bounds__(256) void k_dinv(const int* __restrict__ cnt, float* __restrict__ dinv) {
  int i = blockIdx.x * 256 + threadIdx.x;
  if (i < NN) dinv[i] = rsqrtf((float)(cnt[i] + 1));   // +1 self-loop, always > 0
}

__global__ __launch_bounds__(256) void k_blocksum(const int* __restrict__ cnt, int* __restrict__ bsum) {
  __shared__ int s[256];
  int b = blockIdx.x, t = threadIdx.x;
  int base = b * 1024 + t * 4;
  int tot = 0;
  if (base < NN) { int4 v = *(const int4*)&cnt[base]; tot = v.x + v.y + v.z + v.w; }
  s[t] = tot; __syncthreads();
  for (int o = 128; o > 0; o >>= 1) { if (t < o) s[t] += s[t + o]; __syncthreads(); }
  if (t == 0) bsum[b] = s[0];
}

__global__ __launch_bounds__(128) void k_scanbsum(int* __restrict__ bsum) {
  __shared__ int s[128];
  int t = threadIdx.x;
  int v = (t < NB) ? bsum[t] : 0;
  s[t] = v; __syncthreads();
  for (int o = 1; o < 128; o <<= 1) {
    int add = (t >= o) ? s[t - o] : 0;
    __syncthreads();
    s[t] += add;
    __syncthreads();
  }
  if (t < NB) bsum[t] = s[t] - v;   // exclusive scan of block totals
}

__global__ __launch_bounds__(256) void k_scan3(const int* __restrict__ cnt, const int* __restrict__ bsum,
                                               int* __restrict__ offs, int* __restrict__ cur) {
  __shared__ int s[256];
  int b = blockIdx.x, t = threadIdx.x;
  int base = b * 1024 + t * 4;
  int4 v = make_int4(0, 0, 0, 0);
  if (base < NN) v = *(const int4*)&cnt[base];
  int tot = v.x + v.y + v.z + v.w;
  s[t] = tot; __syncthreads();
  for (int o = 1; o < 256; o <<= 1) {
    int add = (t >= o) ? s[t - o] : 0;
    __syncthreads();
    s[t] += add;
    __syncthreads();
  }
  int tp = s[t] - tot;              // exclusive prefix of thread totals
  int b0 = bsum[b] + tp;
  if (base < NN) {
    int4 o4;
    o4.x = b0;
    o4.y = b0 + v.x;
    o4.z = b0 + v.x + v.y;
    o4.w = b0 + v.x + v.y + v.z;
    *(int4*)&offs[base] = o4;
    *(int4*)&cur[base]  = o4;       // scatter cursor (free copy)
  }
  if (b == 0 && t == 0) offs[NN] = NE;
}

__global__ __launch_bounds__(256) void k_scatter(const int* __restrict__ ei, int* __restrict__ cur,
                                                 const float* __restrict__ dinv, int2* __restrict__ ep) {
  int base = (blockIdx.x * 256 + threadIdx.x) * 4;
  if (base >= NE) return;
  int4 s4 = *(const int4*)&ei[base];
  int4 d4 = *(const int4*)&ei[NE + base];
  int p0 = atomicAdd(&cur[d4.x], 1);
  int p1 = atomicAdd(&cur[d4.y], 1);
  int p2 = atomicAdd(&cur[d4.z], 1);
  int p3 = atomicAdd(&cur[d4.w], 1);
  ep[p0] = make_int2(s4.x, __float_as_int(dinv[s4.x]));
  ep[p1] = make_int2(s4.y, __float_as_int(dinv[s4.y]));
  ep[p2] = make_int2(s4.z, __float_as_int(dinv[s4.z]));
  ep[p3] = make_int2(s4.w, __float_as_int(dinv[s4.w]));
}

// ---------------- W1 -> bf16, transposed: wt[n][k] = bf16(W1[k][n]) ----------------

__global__ __launch_bounds__(256) void k_prepw(const float* __restrict__ W1, u16* __restrict__ wt) {
  int id = blockIdx.x * 256 + threadIdx.x;     // 65536 = 128 * 512
  int k = id & 511, n = id >> 9;
  wt[n * DIN + k] = f2bf(W1[k * DHID + n]);
}

// ---------------- GEMM1 (MFMA, pipelined): h1 = x @ W1, bf16 out ----------------
// Depth-2 register prefetch + double-buffered LDS + RAW barriers.
// Old: stage -> syncthreads (vmcnt(0) drain!) -> MFMA -> syncthreads, single buffer:
// every chunk ate full HBM latency serially (MfmaUtil 4%, VALUBusy 5%, 120 us).
// New schedule per chunk c: issue loads(c+2)->regs | MFMA buf[c&1] | cvt+ds_write
// buf[(c+1)&1] (compiler emits counted vmcnt) | lgkmcnt(0)+sched_barrier+raw s_barrier.
// Global loads stay in flight ACROSS barriers (T4); latency hidden under MFMA+cvt.
// LDS 2x(9.2+18.4)=55.3 KB -> 2 blocks/CU.

#define G1_LOAD(S, C) do { int k0_ = (C) * 64;                                          \
  _Pragma("unroll") for (int it = 0; it < 4; it++) {                                    \
    int u_ = t + it * 256; int row_ = u_ >> 4, seg_ = u_ & 15; int gr_ = row0 + row_;   \
    xv[S][it] = (gr_ < NN) ? *(const float4*)&x[gr_ * DIN + k0_ + seg_ * 4]             \
                           : make_float4(0.f, 0.f, 0.f, 0.f);                           \
    wv[S][it] = *(const uint4*)&wt[(u_ >> 3) * DIN + k0_ + (u_ & 7) * 8];               \
  } } while (0)

#define G1_WRITE(S) do {                                                                \
  _Pragma("unroll") for (int it = 0; it < 4; it++) {                                    \
    int u_ = t + it * 256; int row_ = u_ >> 4, seg_ = u_ & 15;                          \
    float4 v_ = xv[S][it]; ushort4 o_;                                                  \
    o_.x = f2bf(v_.x); o_.y = f2bf(v_.y); o_.z = f2bf(v_.z); o_.w = f2bf(v_.w);         \
    *(ushort4*)&xs[S][row_][seg_ * 4] = o_;                                             \
    *(uint4*)&ws[S][u_ >> 3][(u_ & 7) * 8] = wv[S][it];                                 \
  } } while (0)

#define G1_MFMA(S) do {                                                                 \
  _Pragma("unroll") for (int s2 = 0; s2 < 2; s2++) {                                    \
    short8 a_ = *(const short8*)&xs[S][mbase + lm][s2 * 32 + lq * 8];                   \
    _Pragma("unroll") for (int nt = 0; nt < 8; nt++) {                                  \
      short8 b_ = *(const short8*)&ws[S][nt * 16 + lm][s2 * 32 + lq * 8];               \
      acc[nt] = __builtin_amdgcn_mfma_f32_16x16x32_bf16(a_, b_, acc[nt], 0, 0, 0);      \
    } } } while (0)

#define G1_BAR() do {                                                                   \
    asm volatile("s_waitcnt lgkmcnt(0)" ::: "memory");                                  \
    __builtin_amdgcn_sched_barrier(0); /* rule #18: pin MFMA behind the wait */         \
    __builtin_amdgcn_s_barrier();                                                       \
  } while (0)

__global__ __launch_bounds__(256) void k_gemm1(const float* __restrict__ x, const u16* __restrict__ wt,
                                               u16* __restrict__ h1) {
  __shared__ u16 xs[2][64][72];     // 2 x 9.2 KB, row stride 144 B (16B-aligned, 2-way reads)
  __shared__ u16 ws[2][128][72];    // 2 x 18.4 KB
  int t = threadIdx.x;
  int row0 = blockIdx.x * 64;
  int w = t >> 6, l = t & 63;
  int lm = l & 15, lq = l >> 4;     // col-in-tile / quad
  int mbase = w * 16;
  float4 xv[2][4];
  uint4  wv[2][4];
  f32x4 acc[8];
#pragma unroll
  for (int nt = 0; nt < 8; nt++) acc[nt] = (f32x4){0.f, 0.f, 0.f, 0.f};

  // prologue: chunks 0 and 1 in flight; write chunk 0 to LDS buf0
  G1_LOAD(0, 0);
  G1_LOAD(1, 1);
  G1_WRITE(0);                      // compiler waits only chunk-0 loads (counted vmcnt)
  G1_BAR();

#pragma unroll
  for (int c = 0; c < 8; c++) {
    if (c + 2 < 8) {
      if ((c & 1) == 0) G1_LOAD(0, c + 2); else G1_LOAD(1, c + 2);
    }
    if ((c & 1) == 0) G1_MFMA(0); else G1_MFMA(1);
    if (c + 1 < 8) {
      if ((c & 1) == 0) G1_WRITE(1); else G1_WRITE(0);   // chunk c+1 -> other buffer
      G1_BAR();
    }
  }

  // epilogue: lane holds (row = lq*4+reg, col = lm) of each 16x16 tile
#pragma unroll
  for (int reg = 0; reg < 4; reg++) {
    int gr = row0 + mbase + lq * 4 + reg;
    if (gr < NN) {
#pragma unroll
      for (int nt = 0; nt < 8; nt++) {
        h1[gr * DHID + nt * 16 + lm] = f2bf(acc[nt][reg]);
      }
    }
  }
}

// ---------------- prop1: g = relu(b1 + Ahat @ h1), bf16 intermediate ----------------
// 256-thr block = 4 waves = 4 nodes. Quarter qtr takes contiguous 4-edge chunks;
// lane covers 8 feats (16B gather x 16 lanes = 256B/edge). ~4 gathers in flight/lane
// matches avg degree 16 (whole typical bucket in flight at once).

__global__ __launch_bounds__(256) void k_prop1(const u16* __restrict__ h1, const float* __restrict__ dinv,
                                               const int* __restrict__ offs, const int2* __restrict__ ep,
                                               const float* __restrict__ b1, u16* __restrict__ g) {
  int n = blockIdx.x * 4 + (threadIdx.x >> 6);
  int l = threadIdx.x & 63;
  int qtr = l >> 4, c = l & 15;
  int fb = c * 8;
  float dn = dinv[n];
  float a[8];
#pragma unroll
  for (int j = 0; j < 8; j++) a[j] = 0.f;
  if (qtr == 0) {                      // self-loop: dn * h1[n] (outer dn applied at end)
    short8 sv = *(const short8*)&h1[n * DHID + fb];
#pragma unroll
    for (int j = 0; j < 8; j++) a[j] = dn * bf2f((u16)sv[j]);
  }
  int e1 = offs[n + 1];
  int q = offs[n] + qtr * 4;
  for (; q + 3 < e1; q += 16) {        // full 4-edge chunk for this quarter
    int2 ea = ep[q], eb = ep[q + 1], ec = ep[q + 2], ed = ep[q + 3];
    float wa = __int_as_float(ea.y), wb = __int_as_float(eb.y);
    float wc = __int_as_float(ec.y), wd = __int_as_float(ed.y);
    short8 va = *(const short8*)&h1[ea.x * DHID + fb];
    short8 vb = *(const short8*)&h1[eb.x * DHID + fb];
    short8 vc = *(const short8*)&h1[ec.x * DHID + fb];
    short8 vd = *(const short8*)&h1[ed.x * DHID + fb];
#pragma unroll
    for (int j = 0; j < 8; j++)
      a[j] += wa * bf2f((u16)va[j]) + wb * bf2f((u16)vb[j])
            + wc * bf2f((u16)vc[j]) + wd * bf2f((u16)vd[j]);
  }
  for (; q < e1; q++) {                // partial chunk tail (up to 3 edges)
    int2 ea = ep[q];
    float wa = __int_as_float(ea.y);
    short8 va = *(const short8*)&h1[ea.x * DHID + fb];
#pragma unroll
    for (int j = 0; j < 8; j++) a[j] += wa * bf2f((u16)va[j]);
  }
#pragma unroll
  for (int j = 0; j < 8; j++) {        // reduce across the 4 quarters
    a[j] += __shfl_xor(a[j], 16);
    a[j] += __shfl_xor(a[j], 32);
  }
  if (qtr == 0) {
    float4 b0 = *(const float4*)&b1[fb];
    float4 b4 = *(const float4*)&b1[fb + 4];
    float bb[8] = {b0.x, b0.y, b0.z, b0.w, b4.x, b4.y, b4.z, b4.w};
    short8 o;
#pragma unroll
    for (int j = 0; j < 8; j++) o[j] = (short)f2bf(fmaxf(bb[j] + dn * a[j], 0.f));
    *(short8*)&g[n * DHID + fb] = o;
  }
}

// ---------------- GEMM2: h2[NN][40] = g[NN][128] @ W2[128][40] ----------------

__global__ __launch_bounds__(320) void k_gemm2(const u16* __restrict__ g, const float* __restrict__ W2,
                                               u16* __restrict__ h2) {
  __shared__ float w2s[DHID][DOUT];   // 20 KB
  __shared__ float gs[8][DHID];       // 4 KB
  int t = threadIdx.x;
  int row0 = blockIdx.x * 8;
  for (int idx = t; idx < DHID * DOUT; idx += 320) ((float*)w2s)[idx] = W2[idx];
  for (int idx = t; idx < 8 * DHID; idx += 320) {
    int r = idx >> 7, k = idx & 127;
    int gr = row0 + r;
    ((float*)gs)[idx] = (gr < NN) ? bf2f(g[gr * DHID + k]) : 0.f;
  }
  __syncthreads();
  int r = t / DOUT, c = t % DOUT;     // 8 rows x 40 cols = 320 threads exactly
  float acc = 0.f;
#pragma unroll
  for (int k = 0; k < DHID; k += 4) {
    float4 gv = *(const float4*)&gs[r][k];
    acc += gv.x * w2s[k][c] + gv.y * w2s[k + 1][c] + gv.z * w2s[k + 2][c] + gv.w * w2s[k + 3][c];
  }
  int gr = row0 + r;
  if (gr < NN) h2[gr * DOUT + c] = f2bf(acc);
}

// ---------------- prop2 + log_softmax, fp32 out ----------------
// 256-thr block = 4 waves = 4 nodes. Two 32-lane halves take alternating contiguous
// 4-edge chunks; lane covers a feature PAIR via one uint (20 active lanes x 4B).

__global__ __launch_bounds__(256) void k_prop2(const u16* __restrict__ h2, const float* __restrict__ dinv,
                                               const int* __restrict__ offs, const int2* __restrict__ ep,
                                               const float* __restrict__ b2, float* __restrict__ out) {
  int n = blockIdx.x * 4 + (threadIdx.x >> 6);
  int l = threadIdx.x & 63;
  int grp = l >> 5;                 // which edge-chunk stream
  int c2 = l & 31;                  // feature-pair id; active if < 20
  bool act = c2 < 20;
  int f = c2 * 2;
  float dn = dinv[n];
  float a0 = 0.f, a1 = 0.f;
  if (grp == 0 && act) {            // self-loop
    uint sv = *(const uint*)&h2[n * DOUT + f];
    a0 = dn * bf2f((u16)(sv & 0xffffu));
    a1 = dn * bf2f((u16)(sv >> 16));
  }
  int e1 = offs[n + 1];
  int q = offs[n] + grp * 4;
  for (; q + 3 < e1; q += 8) {      // full 4-edge chunk for this half-wave
    int2 ea = ep[q], eb = ep[q + 1], ec = ep[q + 2], ed = ep[q + 3];
    uint va = act ? *(const uint*)&h2[ea.x * DOUT + f] : 0u;
    uint vb = act ? *(const uint*)&h2[eb.x * DOUT + f] : 0u;
    uint vc = act ? *(const uint*)&h2[ec.x * DOUT + f] : 0u;
    uint vd = act ? *(const uint*)&h2[ed.x * DOUT + f] : 0u;
    float wa = __int_as_float(ea.y), wb = __int_as_float(eb.y);
    float wc = __int_as_float(ec.y), wd = __int_as_float(ed.y);
    a0 += wa * bf2f((u16)(va & 0xffffu)) + wb * bf2f((u16)(vb & 0xffffu))
        + wc * bf2f((u16)(vc & 0xffffu)) + wd * bf2f((u16)(vd & 0xffffu));
    a1 += wa * bf2f((u16)(va >> 16)) + wb * bf2f((u16)(vb >> 16))
        + wc * bf2f((u16)(vc >> 16)) + wd * bf2f((u16)(vd >> 16));
  }
  for (; q < e1; q++) {             // partial chunk tail (up to 3 edges)
    int2 ea = ep[q];
    uint va = act ? *(const uint*)&h2[ea.x * DOUT + f] : 0u;
    float wa = __int_as_float(ea.y);
    a0 += wa * bf2f((u16)(va & 0xffffu));
    a1 += wa * bf2f((u16)(va >> 16));
  }
  a0 += __shfl_xor(a0, 32);         // combine the two edge streams
  a1 += __shfl_xor(a1, 32);
  float l0 = act ? (b2[f]     + dn * a0) : -INFINITY;
  float l1 = act ? (b2[f + 1] + dn * a1) : -INFINITY;
  // both 32-lane halves hold identical logits now -> reduce within each half
  float mx = fmaxf(l0, l1);
#pragma unroll
  for (int o = 16; o > 0; o >>= 1) mx = fmaxf(mx, __shfl_xor(mx, o));
  float pv = act ? (__expf(l0 - mx) + __expf(l1 - mx)) : 0.f;
#pragma unroll
  for (int o = 16; o > 0; o >>= 1) pv += __shfl_xor(pv, o);
  if (grp == 0 && act) {
    float ls = logf(pv);
    *(float2*)&out[n * DOUT + f] = make_float2(l0 - mx - ls, l1 - mx - ls);
  }
}

// ---------------- launch ----------------

extern "C" void kernel_launch(void* const* d_in, const int* in_sizes, int n_in,
                              void* d_out, int out_size, void* d_ws, size_t ws_size,
                              hipStream_t stream) {
  const float* x  = (const float*)d_in[0];   // fp32
  const int* ei   = (const int*)d_in[1];     // int32 on device
  const float* W1 = (const float*)d_in[2];
  const float* b1 = (const float*)d_in[3];
  const float* W2 = (const float*)d_in[4];
  const float* b2 = (const float*)d_in[5];
  float* out      = (float*)d_out;           // fp32 output

  char* ws = (char*)d_ws;
  // layout (bytes): cnt 400000 | dinv 400000 | offs 400128 | bsum 512 |
  //                 ep 12800000 (int2/edge) | cur 400000 |
  //                 h1 25600000 (h2 overlays h1) | g 25600000 | wt 131072
  int*   cnt    = (int*)(ws + 0);
  float* dinv   = (float*)(ws + 400000);
  int*   offs   = (int*)(ws + 800000);
  int*   bsum   = (int*)(ws + 1200128);
  int2*  ep     = (int2*)(ws + 1200640);
  int*   cur    = (int*)(ws + 14000640);
  u16*   h1     = (u16*)(ws + 20400640);
  u16*   h2     = (u16*)(ws + 20400640);     // overlay on h1 (h1 dead after prop1)
  u16*   g      = (u16*)(ws + 46000640);
  u16*   wt     = (u16*)(ws + 71600640);     // W1^T in bf16: [128][512]

  hipMemsetAsync(cnt, 0, 400000, stream);                    // cnt = 0

  k_count   <<<(NE / 4 + 255) / 256, 256, 0, stream>>>(ei, cnt);
  k_dinv    <<<(NN + 255) / 256, 256, 0, stream>>>(cnt, dinv);
  k_blocksum<<<NB, 256, 0, stream>>>(cnt, bsum);
  k_scanbsum<<<1, 128, 0, stream>>>(bsum);
  k_scan3   <<<NB, 256, 0, stream>>>(cnt, bsum, offs, cur);
  k_scatter <<<(NE / 4 + 255) / 256, 256, 0, stream>>>(ei, cur, dinv, ep);

  k_prepw   <<<(DIN * DHID) / 256, 256, 0, stream>>>(W1, wt);
  k_gemm1   <<<(NN + 63) / 64, 256, 0, stream>>>(x, wt, h1);
  k_prop1   <<<NN / 4, 256, 0, stream>>>(h1, dinv, offs, ep, b1, g);
  k_gemm2   <<<(NN + 7) / 8, 320, 0, stream>>>(g, W2, h2);
  k_prop2   <<<NN / 4, 256, 0, stream>>>(h2, dinv, offs, ep, b2, out);
}

// Round 7
// 707.872 us; speedup vs baseline: 1.0369x; 1.0369x over previous
//
#include <hip/hip_runtime.h>
#include <hip/hip_bf16.h>

typedef unsigned short u16;
typedef __attribute__((ext_vector_type(8))) short short8;
typedef __attribute__((ext_vector_type(4))) float f32x4;

#define NN   100000
#define NE   1600000
#define DIN  512
#define DHID 128
#define DOUT 40
#define NB   98          // ceil(NN / 1024) scan blocks

__device__ __forceinline__ float bf2f(u16 u) {
  union { unsigned int i; float f; } v; v.i = ((unsigned int)u) << 16; return v.f;
}
__device__ __forceinline__ u16 f2bf(float f) {
  __hip_bfloat16 h = __float2bfloat16(f);
  return *reinterpret_cast<u16*>(&h);
}

// ---------------- graph build ----------------
// dtypes (HW-verified): ei int32, x/W1/b1/W2/b2 fp32, d_out fp32.
// CSR bucket order is irrelevant (we only sum over edges). k_scatter takes its
// within-bucket slot from an atomicAdd on a cursor array (cur = copy of offs,
// written for free by k_scan3). Edge record packed as int2{src, bits(dinv[src])}.

__global__ __launch_bounds__(256) void k_count(const int* __restrict__ ei, int* __restrict__ cnt) {
  int base = (blockIdx.x * 256 + threadIdx.x) * 4;
  if (base >= NE) return;
  int4 d4 = *(const int4*)&ei[NE + base];
  atomicAdd(&cnt[d4.x], 1);    // 4 independent atomics in flight
  atomicAdd(&cnt[d4.y], 1);
  atomicAdd(&cnt[d4.z], 1);
  atomicAdd(&cnt[d4.w], 1);
}

__global__ __launch_bounds__(256) void k_dinv(const int* __restrict__ cnt, float* __restrict__ dinv) {
  int i = blockIdx.x * 256 + threadIdx.x;
  if (i < NN) dinv[i] = rsqrtf((float)(cnt[i] + 1));   // +1 self-loop, always > 0
}

__global__ __launch_bounds__(256) void k_blocksum(const int* __restrict__ cnt, int* __restrict__ bsum) {
  __shared__ int s[256];
  int b = blockIdx.x, t = threadIdx.x;
  int base = b * 1024 + t * 4;
  int tot = 0;
  if (base < NN) { int4 v = *(const int4*)&cnt[base]; tot = v.x + v.y + v.z + v.w; }
  s[t] = tot; __syncthreads();
  for (int o = 128; o > 0; o >>= 1) { if (t < o) s[t] += s[t + o]; __syncthreads(); }
  if (t == 0) bsum[b] = s[0];
}

__global__ __launch_bounds__(128) void k_scanbsum(int* __restrict__ bsum) {
  __shared__ int s[128];
  int t = threadIdx.x;
  int v = (t < NB) ? bsum[t] : 0;
  s[t] = v; __syncthreads();
  for (int o = 1; o < 128; o <<= 1) {
    int add = (t >= o) ? s[t - o] : 0;
    __syncthreads();
    s[t] += add;
    __syncthreads();
  }
  if (t < NB) bsum[t] = s[t] - v;   // exclusive scan of block totals
}

__global__ __launch_bounds__(256) void k_scan3(const int* __restrict__ cnt, const int* __restrict__ bsum,
                                               int* __restrict__ offs, int* __restrict__ cur) {
  __shared__ int s[256];
  int b = blockIdx.x, t = threadIdx.x;
  int base = b * 1024 + t * 4;
  int4 v = make_int4(0, 0, 0, 0);
  if (base < NN) v = *(const int4*)&cnt[base];
  int tot = v.x + v.y + v.z + v.w;
  s[t] = tot; __syncthreads();
  for (int o = 1; o < 256; o <<= 1) {
    int add = (t >= o) ? s[t - o] : 0;
    __syncthreads();
    s[t] += add;
    __syncthreads();
  }
  int tp = s[t] - tot;              // exclusive prefix of thread totals
  int b0 = bsum[b] + tp;
  if (base < NN) {
    int4 o4;
    o4.x = b0;
    o4.y = b0 + v.x;
    o4.z = b0 + v.x + v.y;
    o4.w = b0 + v.x + v.y + v.z;
    *(int4*)&offs[base] = o4;
    *(int4*)&cur[base]  = o4;       // scatter cursor (free copy)
  }
  if (b == 0 && t == 0) offs[NN] = NE;
}

__global__ __launch_bounds__(256) void k_scatter(const int* __restrict__ ei, int* __restrict__ cur,
                                                 const float* __restrict__ dinv, int2* __restrict__ ep) {
  int base = (blockIdx.x * 256 + threadIdx.x) * 4;
  if (base >= NE) return;
  int4 s4 = *(const int4*)&ei[base];
  int4 d4 = *(const int4*)&ei[NE + base];
  int p0 = atomicAdd(&cur[d4.x], 1);
  int p1 = atomicAdd(&cur[d4.y], 1);
  int p2 = atomicAdd(&cur[d4.z], 1);
  int p3 = atomicAdd(&cur[d4.w], 1);
  ep[p0] = make_int2(s4.x, __float_as_int(dinv[s4.x]));
  ep[p1] = make_int2(s4.y, __float_as_int(dinv[s4.y]));
  ep[p2] = make_int2(s4.z, __float_as_int(dinv[s4.z]));
  ep[p3] = make_int2(s4.w, __float_as_int(dinv[s4.w]));
}

// ---------------- W1 -> bf16, transposed: wt[n][k] = bf16(W1[k][n]) ----------------

__global__ __launch_bounds__(256) void k_prepw(const float* __restrict__ W1, u16* __restrict__ wt) {
  int id = blockIdx.x * 256 + threadIdx.x;     // 65536 = 128 * 512
  int k = id & 511, n = id >> 9;
  wt[n * DIN + k] = f2bf(W1[k * DHID + n]);
}

// ---------------- GEMM1 (MFMA, pipelined v3): h1 = x @ W1, bf16 out ----------------
// Theory: duration tracks per-CU request count (r2 single-buf == r4 pipelined
// == ~125 us; insensitive to occupancy 43%->18.6%). Half of all requests were wt
// re-reads (every block streamed the full 131 KB W1 from L2). This version:
//   M-tile 128 (512 thr, 8 waves; wave w owns rows w*16..+16, all 8 n-tiles)
//     -> wt staging amortized over 2x rows: lane-loads/work -25%, wt traffic -50%
//   BK=32, LDS rows 64 B XOR-swizzled (seg ^= (row>>1)&3): bank-conflict-free
//     without padding; both write & read sides swizzled (reg-staged, rule #21 ok)
//   LDS 2buf x (8+8) KB = 32 KB; __launch_bounds__(512,4) caps VGPR<=128
//     -> 2 blocks x 8 waves = 16 waves/CU (vs 6 in r4)
//   depth-2 register prefetch, lgkmcnt-only raw barriers (loads fly across barriers)

#define G1_LOAD(S, C) do { int k0_ = (C) * 32;                                          \
  _Pragma("unroll") for (int it = 0; it < 2; it++) {                                    \
    int u_ = t + it * 512; int row_ = u_ >> 3, pc_ = u_ & 7; int gr_ = row0 + row_;     \
    xv[S][it] = (gr_ < NN) ? *(const float4*)&x[gr_ * DIN + k0_ + pc_ * 4]              \
                           : make_float4(0.f, 0.f, 0.f, 0.f);                           \
  }                                                                                     \
  wv[S] = *(const uint4*)&wt[(t >> 2) * DIN + k0_ + (t & 3) * 8];                       \
  } while (0)

#define G1_WRITE(S) do {                                                                \
  _Pragma("unroll") for (int it = 0; it < 2; it++) {                                    \
    int u_ = t + it * 512; int row_ = u_ >> 3, pc_ = u_ & 7;                            \
    int sg_ = pc_ >> 1, hf_ = pc_ & 1;                                                  \
    int sw_ = sg_ ^ ((row_ >> 1) & 3);                                                  \
    float4 v_ = xv[S][it]; ushort4 o_;                                                  \
    o_.x = f2bf(v_.x); o_.y = f2bf(v_.y); o_.z = f2bf(v_.z); o_.w = f2bf(v_.w);         \
    *(ushort4*)&xs[S][row_][sw_ * 8 + hf_ * 4] = o_;                                    \
  }                                                                                     \
  { int n_ = t >> 2, sg_ = t & 3; int sw_ = sg_ ^ ((n_ >> 1) & 3);                      \
    *(uint4*)&ws[S][n_][sw_ * 8] = wv[S]; }                                             \
  } while (0)

#define G1_MFMA(S) do {                                                                 \
  int ar_ = mbase + lm;                                                                 \
  short8 a_ = *(const short8*)&xs[S][ar_][(lq ^ ((ar_ >> 1) & 3)) * 8];                 \
  _Pragma("unroll") for (int nt = 0; nt < 8; nt++) {                                    \
    int br_ = nt * 16 + lm;                                                             \
    short8 b_ = *(const short8*)&ws[S][br_][(lq ^ ((br_ >> 1) & 3)) * 8];               \
    acc[nt] = __builtin_amdgcn_mfma_f32_16x16x32_bf16(a_, b_, acc[nt], 0, 0, 0);        \
  } } while (0)

#define G1_BAR() do {                                                                   \
    asm volatile("s_waitcnt lgkmcnt(0)" ::: "memory");                                  \
    __builtin_amdgcn_sched_barrier(0); /* rule #18: pin MFMA behind the wait */         \
    __builtin_amdgcn_s_barrier();                                                       \
  } while (0)

__global__ __launch_bounds__(512, 4) void k_gemm1(const float* __restrict__ x, const u16* __restrict__ wt,
                                                  u16* __restrict__ h1) {
  __shared__ u16 xs[2][128][32];    // 64 B rows, XOR-swizzled 16B segs (8 KB/buf)
  __shared__ u16 ws[2][128][32];    // same layout for W^T                 (8 KB/buf)
  int t = threadIdx.x;
  int row0 = blockIdx.x * 128;
  int w = t >> 6, l = t & 63;
  int lm = l & 15, lq = l >> 4;     // col-in-tile / quad
  int mbase = w * 16;
  float4 xv[2][2];
  uint4  wv[2];
  f32x4 acc[8];
#pragma unroll
  for (int nt = 0; nt < 8; nt++) acc[nt] = (f32x4){0.f, 0.f, 0.f, 0.f};

  // prologue: chunks 0 and 1 in flight; write chunk 0 to LDS buf0
  G1_LOAD(0, 0);
  G1_LOAD(1, 1);
  G1_WRITE(0);                      // compiler waits only chunk-0 loads (counted vmcnt)
  G1_BAR();

#pragma unroll
  for (int c = 0; c < 16; c++) {
    if (c + 2 < 16) {
      if ((c & 1) == 0) G1_LOAD(0, c + 2); else G1_LOAD(1, c + 2);
    }
    if ((c & 1) == 0) G1_MFMA(0); else G1_MFMA(1);
    if (c + 1 < 16) {
      if ((c & 1) == 0) G1_WRITE(1); else G1_WRITE(0);   // chunk c+1 -> other buffer
      G1_BAR();
    }
  }

  // epilogue: lane holds (row = lq*4+reg, col = lm) of each 16x16 tile
#pragma unroll
  for (int reg = 0; reg < 4; reg++) {
    int gr = row0 + mbase + lq * 4 + reg;
    if (gr < NN) {
#pragma unroll
      for (int nt = 0; nt < 8; nt++) {
        h1[gr * DHID + nt * 16 + lm] = f2bf(acc[nt][reg]);
      }
    }
  }
}

// ---------------- prop1: g = relu(b1 + Ahat @ h1), bf16 intermediate ----------------
// 256-thr block = 4 waves = 4 nodes. Quarter qtr takes contiguous 4-edge chunks;
// lane covers 8 feats (16B gather x 16 lanes = 256B/edge). ~4 gathers in flight/lane.

__global__ __launch_bounds__(256) void k_prop1(const u16* __restrict__ h1, const float* __restrict__ dinv,
                                               const int* __restrict__ offs, const int2* __restrict__ ep,
                                               const float* __restrict__ b1, u16* __restrict__ g) {
  int n = blockIdx.x * 4 + (threadIdx.x >> 6);
  int l = threadIdx.x & 63;
  int qtr = l >> 4, c = l & 15;
  int fb = c * 8;
  float dn = dinv[n];
  float a[8];
#pragma unroll
  for (int j = 0; j < 8; j++) a[j] = 0.f;
  if (qtr == 0) {                      // self-loop: dn * h1[n] (outer dn applied at end)
    short8 sv = *(const short8*)&h1[n * DHID + fb];
#pragma unroll
    for (int j = 0; j < 8; j++) a[j] = dn * bf2f((u16)sv[j]);
  }
  int e1 = offs[n + 1];
  int q = offs[n] + qtr * 4;
  for (; q + 3 < e1; q += 16) {        // full 4-edge chunk for this quarter
    int2 ea = ep[q], eb = ep[q + 1], ec = ep[q + 2], ed = ep[q + 3];
    float wa = __int_as_float(ea.y), wb = __int_as_float(eb.y);
    float wc = __int_as_float(ec.y), wd = __int_as_float(ed.y);
    short8 va = *(const short8*)&h1[ea.x * DHID + fb];
    short8 vb = *(const short8*)&h1[eb.x * DHID + fb];
    short8 vc = *(const short8*)&h1[ec.x * DHID + fb];
    short8 vd = *(const short8*)&h1[ed.x * DHID + fb];
#pragma unroll
    for (int j = 0; j < 8; j++)
      a[j] += wa * bf2f((u16)va[j]) + wb * bf2f((u16)vb[j])
            + wc * bf2f((u16)vc[j]) + wd * bf2f((u16)vd[j]);
  }
  for (; q < e1; q++) {                // partial chunk tail (up to 3 edges)
    int2 ea = ep[q];
    float wa = __int_as_float(ea.y);
    short8 va = *(const short8*)&h1[ea.x * DHID + fb];
#pragma unroll
    for (int j = 0; j < 8; j++) a[j] += wa * bf2f((u16)va[j]);
  }
#pragma unroll
  for (int j = 0; j < 8; j++) {        // reduce across the 4 quarters
    a[j] += __shfl_xor(a[j], 16);
    a[j] += __shfl_xor(a[j], 32);
  }
  if (qtr == 0) {
    float4 b0 = *(const float4*)&b1[fb];
    float4 b4 = *(const float4*)&b1[fb + 4];
    float bb[8] = {b0.x, b0.y, b0.z, b0.w, b4.x, b4.y, b4.z, b4.w};
    short8 o;
#pragma unroll
    for (int j = 0; j < 8; j++) o[j] = (short)f2bf(fmaxf(bb[j] + dn * a[j], 0.f));
    *(short8*)&g[n * DHID + fb] = o;
  }
}

// ---------------- GEMM2: h2[NN][40] = g[NN][128] @ W2[128][40] ----------------

__global__ __launch_bounds__(320) void k_gemm2(const u16* __restrict__ g, const float* __restrict__ W2,
                                               u16* __restrict__ h2) {
  __shared__ float w2s[DHID][DOUT];   // 20 KB
  __shared__ float gs[8][DHID];       // 4 KB
  int t = threadIdx.x;
  int row0 = blockIdx.x * 8;
  for (int idx = t; idx < DHID * DOUT; idx += 320) ((float*)w2s)[idx] = W2[idx];
  for (int idx = t; idx < 8 * DHID; idx += 320) {
    int r = idx >> 7, k = idx & 127;
    int gr = row0 + r;
    ((float*)gs)[idx] = (gr < NN) ? bf2f(g[gr * DHID + k]) : 0.f;
  }
  __syncthreads();
  int r = t / DOUT, c = t % DOUT;     // 8 rows x 40 cols = 320 threads exactly
  float acc = 0.f;
#pragma unroll
  for (int k = 0; k < DHID; k += 4) {
    float4 gv = *(const float4*)&gs[r][k];
    acc += gv.x * w2s[k][c] + gv.y * w2s[k + 1][c] + gv.z * w2s[k + 2][c] + gv.w * w2s[k + 3][c];
  }
  int gr = row0 + r;
  if (gr < NN) h2[gr * DOUT + c] = f2bf(acc);
}

// ---------------- prop2 + log_softmax, fp32 out ----------------
// 256-thr block = 4 waves = 4 nodes. Two 32-lane halves take alternating contiguous
// 4-edge chunks; lane covers a feature PAIR via one uint (20 active lanes x 4B).

__global__ __launch_bounds__(256) void k_prop2(const u16* __restrict__ h2, const float* __restrict__ dinv,
                                               const int* __restrict__ offs, const int2* __restrict__ ep,
                                               const float* __restrict__ b2, float* __restrict__ out) {
  int n = blockIdx.x * 4 + (threadIdx.x >> 6);
  int l = threadIdx.x & 63;
  int grp = l >> 5;                 // which edge-chunk stream
  int c2 = l & 31;                  // feature-pair id; active if < 20
  bool act = c2 < 20;
  int f = c2 * 2;
  float dn = dinv[n];
  float a0 = 0.f, a1 = 0.f;
  if (grp == 0 && act) {            // self-loop
    uint sv = *(const uint*)&h2[n * DOUT + f];
    a0 = dn * bf2f((u16)(sv & 0xffffu));
    a1 = dn * bf2f((u16)(sv >> 16));
  }
  int e1 = offs[n + 1];
  int q = offs[n] + grp * 4;
  for (; q + 3 < e1; q += 8) {      // full 4-edge chunk for this half-wave
    int2 ea = ep[q], eb = ep[q + 1], ec = ep[q + 2], ed = ep[q + 3];
    uint va = act ? *(const uint*)&h2[ea.x * DOUT + f] : 0u;
    uint vb = act ? *(const uint*)&h2[eb.x * DOUT + f] : 0u;
    uint vc = act ? *(const uint*)&h2[ec.x * DOUT + f] : 0u;
    uint vd = act ? *(const uint*)&h2[ed.x * DOUT + f] : 0u;
    float wa = __int_as_float(ea.y), wb = __int_as_float(eb.y);
    float wc = __int_as_float(ec.y), wd = __int_as_float(ed.y);
    a0 += wa * bf2f((u16)(va & 0xffffu)) + wb * bf2f((u16)(vb & 0xffffu))
        + wc * bf2f((u16)(vc & 0xffffu)) + wd * bf2f((u16)(vd & 0xffffu));
    a1 += wa * bf2f((u16)(va >> 16)) + wb * bf2f((u16)(vb >> 16))
        + wc * bf2f((u16)(vc >> 16)) + wd * bf2f((u16)(vd >> 16));
  }
  for (; q < e1; q++) {             // partial chunk tail (up to 3 edges)
    int2 ea = ep[q];
    uint va = act ? *(const uint*)&h2[ea.x * DOUT + f] : 0u;
    float wa = __int_as_float(ea.y);
    a0 += wa * bf2f((u16)(va & 0xffffu));
    a1 += wa * bf2f((u16)(va >> 16));
  }
  a0 += __shfl_xor(a0, 32);         // combine the two edge streams
  a1 += __shfl_xor(a1, 32);
  float l0 = act ? (b2[f]     + dn * a0) : -INFINITY;
  float l1 = act ? (b2[f + 1] + dn * a1) : -INFINITY;
  // both 32-lane halves hold identical logits now -> reduce within each half
  float mx = fmaxf(l0, l1);
#pragma unroll
  for (int o = 16; o > 0; o >>= 1) mx = fmaxf(mx, __shfl_xor(mx, o));
  float pv = act ? (__expf(l0 - mx) + __expf(l1 - mx)) : 0.f;
#pragma unroll
  for (int o = 16; o > 0; o >>= 1) pv += __shfl_xor(pv, o);
  if (grp == 0 && act) {
    float ls = logf(pv);
    *(float2*)&out[n * DOUT + f] = make_float2(l0 - mx - ls, l1 - mx - ls);
  }
}

// ---------------- launch ----------------

extern "C" void kernel_launch(void* const* d_in, const int* in_sizes, int n_in,
                              void* d_out, int out_size, void* d_ws, size_t ws_size,
                              hipStream_t stream) {
  const float* x  = (const float*)d_in[0];   // fp32
  const int* ei   = (const int*)d_in[1];     // int32 on device
  const float* W1 = (const float*)d_in[2];
  const float* b1 = (const float*)d_in[3];
  const float* W2 = (const float*)d_in[4];
  const float* b2 = (const float*)d_in[5];
  float* out      = (float*)d_out;           // fp32 output

  char* ws = (char*)d_ws;
  // layout (bytes): cnt 400000 | dinv 400000 | offs 400128 | bsum 512 |
  //                 ep 12800000 (int2/edge) | cur 400000 |
  //                 h1 25600000 (h2 overlays h1) | g 25600000 | wt 131072
  int*   cnt    = (int*)(ws + 0);
  float* dinv   = (float*)(ws + 400000);
  int*   offs   = (int*)(ws + 800000);
  int*   bsum   = (int*)(ws + 1200128);
  int2*  ep     = (int2*)(ws + 1200640);
  int*   cur    = (int*)(ws + 14000640);
  u16*   h1     = (u16*)(ws + 20400640);
  u16*   h2     = (u16*)(ws + 20400640);     // overlay on h1 (h1 dead after prop1)
  u16*   g      = (u16*)(ws + 46000640);
  u16*   wt     = (u16*)(ws + 71600640);     // W1^T in bf16: [128][512]

  hipMemsetAsync(cnt, 0, 400000, stream);                    // cnt = 0

  k_count   <<<(NE / 4 + 255) / 256, 256, 0, stream>>>(ei, cnt);
  k_dinv    <<<(NN + 255) / 256, 256, 0, stream>>>(cnt, dinv);
  k_blocksum<<<NB, 256, 0, stream>>>(cnt, bsum);
  k_scanbsum<<<1, 128, 0, stream>>>(bsum);
  k_scan3   <<<NB, 256, 0, stream>>>(cnt, bsum, offs, cur);
  k_scatter <<<(NE / 4 + 255) / 256, 256, 0, stream>>>(ei, cur, dinv, ep);

  k_prepw   <<<(DIN * DHID) / 256, 256, 0, stream>>>(W1, wt);
  k_gemm1   <<<(NN + 127) / 128, 512, 0, stream>>>(x, wt, h1);
  k_prop1   <<<NN / 4, 256, 0, stream>>>(h1, dinv, offs, ep, b1, g);
  k_gemm2   <<<(NN + 7) / 8, 320, 0, stream>>>(g, W2, h2);
  k_prop2   <<<NN / 4, 256, 0, stream>>>(h2, dinv, offs, ep, b2, out);
}

// Round 10
// 657.371 us; speedup vs baseline: 1.1166x; 1.0768x over previous
//
#include <hip/hip_runtime.h>
#include <hip/hip_bf16.h>

typedef unsigned short u16;
typedef __attribute__((ext_vector_type(8))) short short8;
typedef __attribute__((ext_vector_type(4))) float f32x4;

#define NN   100000
#define NE   1600000
#define DIN  512
#define DHID 128
#define DOUT 40
#define NB   98          // ceil(NN / 1024) scan blocks

__device__ __forceinline__ float bf2f(u16 u) {
  union { unsigned int i; float f; } v; v.i = ((unsigned int)u) << 16; return v.f;
}
__device__ __forceinline__ u16 f2bf(float f) {
  __hip_bfloat16 h = __float2bfloat16(f);
  return *reinterpret_cast<u16*>(&h);
}

// ---------------- graph build ----------------
// dtypes (HW-verified): ei int32, x/W1/b1/W2/b2 fp32, d_out fp32.
// r8: REVERTED to the r2 measured-good structure. The r3 "cursor atomics in
// scatter" redesign cost ~50 us (r2 672 -> r4 734 with only +10 from gemm1):
// each ep store chained on an atomic-with-return round-trip; r2's ticket array
// is a coalesced int4 load instead. CSR bucket order is irrelevant (sum over
// edges), so k_count's atomicAdd return doubles as the within-bucket ticket.
// Edge record packed as int2{src, float_bits(dinv[src])}: ONE 8B scattered
// store per edge, ONE 8B load per edge in the props.

__global__ __launch_bounds__(256) void k_count(const int* __restrict__ ei, int* __restrict__ cnt,
                                               int* __restrict__ ticket) {
  int base = (blockIdx.x * 256 + threadIdx.x) * 4;
  if (base >= NE) return;
  int4 d4 = *(const int4*)&ei[NE + base];
  int t0 = atomicAdd(&cnt[d4.x], 1);    // 4 independent atomics in flight
  int t1 = atomicAdd(&cnt[d4.y], 1);
  int t2 = atomicAdd(&cnt[d4.z], 1);
  int t3 = atomicAdd(&cnt[d4.w], 1);
  *(int4*)&ticket[base] = make_int4(t0, t1, t2, t3);
}

__global__ __launch_bounds__(256) void k_dinv(const int* __restrict__ cnt, float* __restrict__ dinv) {
  int i = blockIdx.x * 256 + threadIdx.x;
  if (i < NN) dinv[i] = rsqrtf((float)(cnt[i] + 1));   // +1 self-loop, always > 0
}

__global__ __launch_bounds__(256) void k_blocksum(const int* __restrict__ cnt, int* __restrict__ bsum) {
  __shared__ int s[256];
  int b = blockIdx.x, t = threadIdx.x;
  int base = b * 1024 + t * 4;
  int tot = 0;
  if (base < NN) { int4 v = *(const int4*)&cnt[base]; tot = v.x + v.y + v.z + v.w; }
  s[t] = tot; __syncthreads();
  for (int o = 128; o > 0; o >>= 1) { if (t < o) s[t] += s[t + o]; __syncthreads(); }
  if (t == 0) bsum[b] = s[0];
}

__global__ __launch_bounds__(128) void k_scanbsum(int* __restrict__ bsum) {
  __shared__ int s[128];
  int t = threadIdx.x;
  int v = (t < NB) ? bsum[t] : 0;
  s[t] = v; __syncthreads();
  for (int o = 1; o < 128; o <<= 1) {
    int add = (t >= o) ? s[t - o] : 0;
    __syncthreads();
    s[t] += add;
    __syncthreads();
  }
  if (t < NB) bsum[t] = s[t] - v;   // exclusive scan of block totals
}

__global__ __launch_bounds__(256) void k_scan3(const int* __restrict__ cnt, const int* __restrict__ bsum,
                                               int* __restrict__ offs) {
  __shared__ int s[256];
  int b = blockIdx.x, t = threadIdx.x;
  int base = b * 1024 + t * 4;
  int4 v = make_int4(0, 0, 0, 0);
  if (base < NN) v = *(const int4*)&cnt[base];
  int tot = v.x + v.y + v.z + v.w;
  s[t] = tot; __syncthreads();
  for (int o = 1; o < 256; o <<= 1) {
    int add = (t >= o) ? s[t - o] : 0;
    __syncthreads();
    s[t] += add;
    __syncthreads();
  }
  int tp = s[t] - tot;              // exclusive prefix of thread totals
  int b0 = bsum[b] + tp;
  if (base < NN) {
    int4 o4;
    o4.x = b0;
    o4.y = b0 + v.x;
    o4.z = b0 + v.x + v.y;
    o4.w = b0 + v.x + v.y + v.z;
    *(int4*)&offs[base] = o4;
  }
  if (b == 0 && t == 0) offs[NN] = NE;
}

__global__ __launch_bounds__(256) void k_scatter(const int* __restrict__ ei, const int* __restrict__ offs,
                                                 const int* __restrict__ ticket, const float* __restrict__ dinv,
                                                 int2* __restrict__ ep) {
  int base = (blockIdx.x * 256 + threadIdx.x) * 4;
  if (base >= NE) return;
  int4 s4 = *(const int4*)&ei[base];
  int4 d4 = *(const int4*)&ei[NE + base];
  int4 t4 = *(const int4*)&ticket[base];
  int p0 = offs[d4.x] + t4.x;
  int p1 = offs[d4.y] + t4.y;
  int p2 = offs[d4.z] + t4.z;
  int p3 = offs[d4.w] + t4.w;
  ep[p0] = make_int2(s4.x, __float_as_int(dinv[s4.x]));
  ep[p1] = make_int2(s4.y, __float_as_int(dinv[s4.y]));
  ep[p2] = make_int2(s4.z, __float_as_int(dinv[s4.z]));
  ep[p3] = make_int2(s4.w, __float_as_int(dinv[s4.w]));
}

// ---------------- W1 -> bf16, transposed: wt[n][k] = bf16(W1[k][n]) ----------------

__global__ __launch_bounds__(256) void k_prepw(const float* __restrict__ W1, u16* __restrict__ wt) {
  int id = blockIdx.x * 256 + threadIdx.x;     // 65536 = 128 * 512
  int k = id & 511, n = id >> 9;
  wt[n * DIN + k] = f2bf(W1[k * DHID + n]);
}

// ---------------- GEMM1 (MFMA, pipelined v3): h1 = x @ W1, bf16 out ----------------
// r7 profile: gemm1 dropped below the 119-us top-5 cutoff (was 120-130) -> v3
// direction confirmed. Structure: M-tile 128 (512 thr, 8 waves; wt staging
// amortized over 2x rows), BK=32, XOR-swizzled 64 B LDS rows (write & read side
// same involution, reg-staged), LDS 32 KB, launch_bounds(512,4) -> 16 waves/CU,
// depth-2 register prefetch, lgkmcnt-only raw barriers (loads fly across barriers).

#define G1_LOAD(S, C) do { int k0_ = (C) * 32;                                          \
  _Pragma("unroll") for (int it = 0; it < 2; it++) {                                    \
    int u_ = t + it * 512; int row_ = u_ >> 3, pc_ = u_ & 7; int gr_ = row0 + row_;     \
    xv[S][it] = (gr_ < NN) ? *(const float4*)&x[gr_ * DIN + k0_ + pc_ * 4]              \
                           : make_float4(0.f, 0.f, 0.f, 0.f);                           \
  }                                                                                     \
  wv[S] = *(const uint4*)&wt[(t >> 2) * DIN + k0_ + (t & 3) * 8];                       \
  } while (0)

#define G1_WRITE(S) do {                                                                \
  _Pragma("unroll") for (int it = 0; it < 2; it++) {                                    \
    int u_ = t + it * 512; int row_ = u_ >> 3, pc_ = u_ & 7;                            \
    int sg_ = pc_ >> 1, hf_ = pc_ & 1;                                                  \
    int sw_ = sg_ ^ ((row_ >> 1) & 3);                                                  \
    float4 v_ = xv[S][it]; ushort4 o_;                                                  \
    o_.x = f2bf(v_.x); o_.y = f2bf(v_.y); o_.z = f2bf(v_.z); o_.w = f2bf(v_.w);         \
    *(ushort4*)&xs[S][row_][sw_ * 8 + hf_ * 4] = o_;                                    \
  }                                                                                     \
  { int n_ = t >> 2, sg_ = t & 3; int sw_ = sg_ ^ ((n_ >> 1) & 3);                      \
    *(uint4*)&ws[S][n_][sw_ * 8] = wv[S]; }                                             \
  } while (0)

#define G1_MFMA(S) do {                                                                 \
  int ar_ = mbase + lm;                                                                 \
  short8 a_ = *(const short8*)&xs[S][ar_][(lq ^ ((ar_ >> 1) & 3)) * 8];                 \
  _Pragma("unroll") for (int nt = 0; nt < 8; nt++) {                                    \
    int br_ = nt * 16 + lm;                                                             \
    short8 b_ = *(const short8*)&ws[S][br_][(lq ^ ((br_ >> 1) & 3)) * 8];               \
    acc[nt] = __builtin_amdgcn_mfma_f32_16x16x32_bf16(a_, b_, acc[nt], 0, 0, 0);        \
  } } while (0)

#define G1_BAR() do {                                                                   \
    asm volatile("s_waitcnt lgkmcnt(0)" ::: "memory");                                  \
    __builtin_amdgcn_sched_barrier(0); /* rule #18: pin MFMA behind the wait */         \
    __builtin_amdgcn_s_barrier();                                                       \
  } while (0)

__global__ __launch_bounds__(512, 4) void k_gemm1(const float* __restrict__ x, const u16* __restrict__ wt,
                                                  u16* __restrict__ h1) {
  __shared__ u16 xs[2][128][32];    // 64 B rows, XOR-swizzled 16B segs (8 KB/buf)
  __shared__ u16 ws[2][128][32];    // same layout for W^T                 (8 KB/buf)
  int t = threadIdx.x;
  int row0 = blockIdx.x * 128;
  int w = t >> 6, l = t & 63;
  int lm = l & 15, lq = l >> 4;     // col-in-tile / quad
  int mbase = w * 16;
  float4 xv[2][2];
  uint4  wv[2];
  f32x4 acc[8];
#pragma unroll
  for (int nt = 0; nt < 8; nt++) acc[nt] = (f32x4){0.f, 0.f, 0.f, 0.f};

  // prologue: chunks 0 and 1 in flight; write chunk 0 to LDS buf0
  G1_LOAD(0, 0);
  G1_LOAD(1, 1);
  G1_WRITE(0);                      // compiler waits only chunk-0 loads (counted vmcnt)
  G1_BAR();

#pragma unroll
  for (int c = 0; c < 16; c++) {
    if (c + 2 < 16) {
      if ((c & 1) == 0) G1_LOAD(0, c + 2); else G1_LOAD(1, c + 2);
    }
    if ((c & 1) == 0) G1_MFMA(0); else G1_MFMA(1);
    if (c + 1 < 16) {
      if ((c & 1) == 0) G1_WRITE(1); else G1_WRITE(0);   // chunk c+1 -> other buffer
      G1_BAR();
    }
  }

  // epilogue: lane holds (row = lq*4+reg, col = lm) of each 16x16 tile
#pragma unroll
  for (int reg = 0; reg < 4; reg++) {
    int gr = row0 + mbase + lq * 4 + reg;
    if (gr < NN) {
#pragma unroll
      for (int nt = 0; nt < 8; nt++) {
        h1[gr * DHID + nt * 16 + lm] = f2bf(acc[nt][reg]);
      }
    }
  }
}

// ---------------- prop1: g = relu(b1 + Ahat @ h1), bf16 intermediate ----------------
// 256-thr block = 4 waves = 4 nodes. Quarter qtr takes contiguous 4-edge chunks;
// lane covers 8 feats (16B gather x 16 lanes = 256B/edge). ~4 gathers in flight/lane.

__global__ __launch_bounds__(256) void k_prop1(const u16* __restrict__ h1, const float* __restrict__ dinv,
                                               const int* __restrict__ offs, const int2* __restrict__ ep,
                                               const float* __restrict__ b1, u16* __restrict__ g) {
  int n = blockIdx.x * 4 + (threadIdx.x >> 6);
  int l = threadIdx.x & 63;
  int qtr = l >> 4, c = l & 15;
  int fb = c * 8;
  float dn = dinv[n];
  float a[8];
#pragma unroll
  for (int j = 0; j < 8; j++) a[j] = 0.f;
  if (qtr == 0) {                      // self-loop: dn * h1[n] (outer dn applied at end)
    short8 sv = *(const short8*)&h1[n * DHID + fb];
#pragma unroll
    for (int j = 0; j < 8; j++) a[j] = dn * bf2f((u16)sv[j]);
  }
  int e1 = offs[n + 1];
  int q = offs[n] + qtr * 4;
  for (; q + 3 < e1; q += 16) {        // full 4-edge chunk for this quarter
    int2 ea = ep[q], eb = ep[q + 1], ec = ep[q + 2], ed = ep[q + 3];
    float wa = __int_as_float(ea.y), wb = __int_as_float(eb.y);
    float wc = __int_as_float(ec.y), wd = __int_as_float(ed.y);
    short8 va = *(const short8*)&h1[ea.x * DHID + fb];
    short8 vb = *(const short8*)&h1[eb.x * DHID + fb];
    short8 vc = *(const short8*)&h1[ec.x * DHID + fb];
    short8 vd = *(const short8*)&h1[ed.x * DHID + fb];
#pragma unroll
    for (int j = 0; j < 8; j++)
      a[j] += wa * bf2f((u16)va[j]) + wb * bf2f((u16)vb[j])
            + wc * bf2f((u16)vc[j]) + wd * bf2f((u16)vd[j]);
  }
  for (; q < e1; q++) {                // partial chunk tail (up to 3 edges)
    int2 ea = ep[q];
    float wa = __int_as_float(ea.y);
    short8 va = *(const short8*)&h1[ea.x * DHID + fb];
#pragma unroll
    for (int j = 0; j < 8; j++) a[j] += wa * bf2f((u16)va[j]);
  }
#pragma unroll
  for (int j = 0; j < 8; j++) {        // reduce across the 4 quarters
    a[j] += __shfl_xor(a[j], 16);
    a[j] += __shfl_xor(a[j], 32);
  }
  if (qtr == 0) {
    float4 b0 = *(const float4*)&b1[fb];
    float4 b4 = *(const float4*)&b1[fb + 4];
    float bb[8] = {b0.x, b0.y, b0.z, b0.w, b4.x, b4.y, b4.z, b4.w};
    short8 o;
#pragma unroll
    for (int j = 0; j < 8; j++) o[j] = (short)f2bf(fmaxf(bb[j] + dn * a[j], 0.f));
    *(short8*)&g[n * DHID + fb] = o;
  }
}

// ---------------- GEMM2: h2[NN][40] = g[NN][128] @ W2[128][40] ----------------

__global__ __launch_bounds__(320) void k_gemm2(const u16* __restrict__ g, const float* __restrict__ W2,
                                               u16* __restrict__ h2) {
  __shared__ float w2s[DHID][DOUT];   // 20 KB
  __shared__ float gs[8][DHID];       // 4 KB
  int t = threadIdx.x;
  int row0 = blockIdx.x * 8;
  for (int idx = t; idx < DHID * DOUT; idx += 320) ((float*)w2s)[idx] = W2[idx];
  for (int idx = t; idx < 8 * DHID; idx += 320) {
    int r = idx >> 7, k = idx & 127;
    int gr = row0 + r;
    ((float*)gs)[idx] = (gr < NN) ? bf2f(g[gr * DHID + k]) : 0.f;
  }
  __syncthreads();
  int r = t / DOUT, c = t % DOUT;     // 8 rows x 40 cols = 320 threads exactly
  float acc = 0.f;
#pragma unroll
  for (int k = 0; k < DHID; k += 4) {
    float4 gv = *(const float4*)&gs[r][k];
    acc += gv.x * w2s[k][c] + gv.y * w2s[k + 1][c] + gv.z * w2s[k + 2][c] + gv.w * w2s[k + 3][c];
  }
  int gr = row0 + r;
  if (gr < NN) h2[gr * DOUT + c] = f2bf(acc);
}

// ---------------- prop2 + log_softmax, fp32 out ----------------
// 256-thr block = 4 waves = 4 nodes. Two 32-lane halves take alternating contiguous
// 4-edge chunks; lane covers a feature PAIR via one uint (20 active lanes x 4B).

__global__ __launch_bounds__(256) void k_prop2(const u16* __restrict__ h2, const float* __restrict__ dinv,
                                               const int* __restrict__ offs, const int2* __restrict__ ep,
                                               const float* __restrict__ b2, float* __restrict__ out) {
  int n = blockIdx.x * 4 + (threadIdx.x >> 6);
  int l = threadIdx.x & 63;
  int grp = l >> 5;                 // which edge-chunk stream
  int c2 = l & 31;                  // feature-pair id; active if < 20
  bool act = c2 < 20;
  int f = c2 * 2;
  float dn = dinv[n];
  float a0 = 0.f, a1 = 0.f;
  if (grp == 0 && act) {            // self-loop
    uint sv = *(const uint*)&h2[n * DOUT + f];
    a0 = dn * bf2f((u16)(sv & 0xffffu));
    a1 = dn * bf2f((u16)(sv >> 16));
  }
  int e1 = offs[n + 1];
  int q = offs[n] + grp * 4;
  for (; q + 3 < e1; q += 8) {      // full 4-edge chunk for this half-wave
    int2 ea = ep[q], eb = ep[q + 1], ec = ep[q + 2], ed = ep[q + 3];
    uint va = act ? *(const uint*)&h2[ea.x * DOUT + f] : 0u;
    uint vb = act ? *(const uint*)&h2[eb.x * DOUT + f] : 0u;
    uint vc = act ? *(const uint*)&h2[ec.x * DOUT + f] : 0u;
    uint vd = act ? *(const uint*)&h2[ed.x * DOUT + f] : 0u;
    float wa = __int_as_float(ea.y), wb = __int_as_float(eb.y);
    float wc = __int_as_float(ec.y), wd = __int_as_float(ed.y);
    a0 += wa * bf2f((u16)(va & 0xffffu)) + wb * bf2f((u16)(vb & 0xffffu))
        + wc * bf2f((u16)(vc & 0xffffu)) + wd * bf2f((u16)(vd & 0xffffu));
    a1 += wa * bf2f((u16)(va >> 16)) + wb * bf2f((u16)(vb >> 16))
        + wc * bf2f((u16)(vc >> 16)) + wd * bf2f((u16)(vd >> 16));
  }
  for (; q < e1; q++) {             // partial chunk tail (up to 3 edges)
    int2 ea = ep[q];
    uint va = act ? *(const uint*)&h2[ea.x * DOUT + f] : 0u;
    float wa = __int_as_float(ea.y);
    a0 += wa * bf2f((u16)(va & 0xffffu));
    a1 += wa * bf2f((u16)(va >> 16));
  }
  a0 += __shfl_xor(a0, 32);         // combine the two edge streams
  a1 += __shfl_xor(a1, 32);
  float l0 = act ? (b2[f]     + dn * a0) : -INFINITY;
  float l1 = act ? (b2[f + 1] + dn * a1) : -INFINITY;
  // both 32-lane halves hold identical logits now -> reduce within each half
  float mx = fmaxf(l0, l1);
#pragma unroll
  for (int o = 16; o > 0; o >>= 1) mx = fmaxf(mx, __shfl_xor(mx, o));
  float pv = act ? (__expf(l0 - mx) + __expf(l1 - mx)) : 0.f;
#pragma unroll
  for (int o = 16; o > 0; o >>= 1) pv += __shfl_xor(pv, o);
  if (grp == 0 && act) {
    float ls = logf(pv);
    *(float2*)&out[n * DOUT + f] = make_float2(l0 - mx - ls, l1 - mx - ls);
  }
}

// ---------------- launch ----------------

extern "C" void kernel_launch(void* const* d_in, const int* in_sizes, int n_in,
                              void* d_out, int out_size, void* d_ws, size_t ws_size,
                              hipStream_t stream) {
  const float* x  = (const float*)d_in[0];   // fp32
  const int* ei   = (const int*)d_in[1];     // int32 on device
  const float* W1 = (const float*)d_in[2];
  const float* b1 = (const float*)d_in[3];
  const float* W2 = (const float*)d_in[4];
  const float* b2 = (const float*)d_in[5];
  float* out      = (float*)d_out;           // fp32 output

  char* ws = (char*)d_ws;
  // layout (bytes): cnt 400000 | dinv 400000 | offs 400128 | bsum 512 |
  //                 ep 12800000 (int2/edge) | ticket 6400000 |
  //                 h1 25600000 (h2 overlays h1) | g 25600000 | wt 131072
  int*   cnt    = (int*)(ws + 0);
  float* dinv   = (float*)(ws + 400000);
  int*   offs   = (int*)(ws + 800000);
  int*   bsum   = (int*)(ws + 1200128);
  int2*  ep     = (int2*)(ws + 1200640);
  int*   ticket = (int*)(ws + 14000640);
  u16*   h1     = (u16*)(ws + 20400640);
  u16*   h2     = (u16*)(ws + 20400640);     // overlay on h1 (h1 dead after prop1)
  u16*   g      = (u16*)(ws + 46000640);
  u16*   wt     = (u16*)(ws + 71600640);     // W1^T in bf16: [128][512]

  hipMemsetAsync(cnt, 0, 400000, stream);                    // cnt = 0

  k_count   <<<(NE / 4 + 255) / 256, 256, 0, stream>>>(ei, cnt, ticket);
  k_dinv    <<<(NN + 255) / 256, 256, 0, stream>>>(cnt, dinv);
  k_blocksum<<<NB, 256, 0, stream>>>(cnt, bsum);
  k_scanbsum<<<1, 128, 0, stream>>>(bsum);
  k_scan3   <<<NB, 256, 0, stream>>>(cnt, bsum, offs);
  k_scatter <<<(NE / 4 + 255) / 256, 256, 0, stream>>>(ei, offs, ticket, dinv, ep);

  k_prepw   <<<(DIN * DHID) / 256, 256, 0, stream>>>(W1, wt);
  k_gemm1   <<<(NN + 127) / 128, 512, 0, stream>>>(x, wt, h1);
  k_prop1   <<<NN / 4, 256, 0, stream>>>(h1, dinv, offs, ep, b1, g);
  k_gemm2   <<<(NN + 7) / 8, 320, 0, stream>>>(g, W2, h2);
  k_prop2   <<<NN / 4, 256, 0, stream>>>(h2, dinv, offs, ep, b2, out);
}